// Round 1
// baseline (219.243 us; speedup 1.0000x reference)
//
#include <hip/hip_runtime.h>
#include <math.h>

#define BB 32
#define CC 256
#define NN 1024
#define BN 32
#define KT_STRIDE 264
#define VT_STRIDE 40
#define PT_STRIDE 40

typedef unsigned short u16;
typedef u16 u16x8 __attribute__((ext_vector_type(8)));
typedef __bf16 bf16x8 __attribute__((ext_vector_type(8)));
typedef float f32x4 __attribute__((ext_vector_type(4)));

__device__ __forceinline__ u16 f2bf(float f) {
    unsigned u = __builtin_bit_cast(unsigned, f);
    return (u16)((u + 0x7FFFu + ((u >> 16) & 1u)) >> 16);
}
__device__ __forceinline__ float bf2f(u16 h) {
    return __builtin_bit_cast(float, ((unsigned)h) << 16);
}
__device__ __forceinline__ bf16x8 ld8(const u16* p) {
    return __builtin_bit_cast(bf16x8, *(const u16x8*)p);
}
__device__ __forceinline__ f32x4 mfma16(bf16x8 a, bf16x8 b, f32x4 c) {
    return __builtin_amdgcn_mfma_f32_16x16x32_bf16(a, b, c, 0, 0, 0);
}

// ---------------------------------------------------------------------------
// Kernel 1: transpose x[b][c][p] (fp32) -> qhi/qlo [b][p][c] (bf16 hi/lo split)
// ---------------------------------------------------------------------------
__global__ __launch_bounds__(256) void k_split(const float* __restrict__ x,
                                               u16* __restrict__ qhi,
                                               u16* __restrict__ qlo) {
    __shared__ float lds[64][65];  // [p][c], pad 65 to spread banks
    int bid = blockIdx.x;
    int b = bid >> 6, ct = (bid >> 4) & 3, pt = bid & 15;
    int t = threadIdx.x;
    int c0 = ct * 64, p0 = pt * 64;
    const float* xb = x + ((size_t)b * CC + c0) * NN + p0;
#pragma unroll
    for (int it = 0; it < 4; ++it) {
        int cl = (t >> 4) + it * 16;
        int pl = (t & 15) * 4;
        float4 v = *(const float4*)(xb + (size_t)cl * NN + pl);
        lds[pl + 0][cl] = v.x;
        lds[pl + 1][cl] = v.y;
        lds[pl + 2][cl] = v.z;
        lds[pl + 3][cl] = v.w;
    }
    __syncthreads();
    u16* qhb = qhi + ((size_t)b * NN + p0) * CC + c0;
    u16* qlb = qlo + ((size_t)b * NN + p0) * CC + c0;
#pragma unroll
    for (int it = 0; it < 2; ++it) {
        int pl = (t >> 3) + it * 32;
        int cl = (t & 7) * 8;
        u16x8 hv, lv;
#pragma unroll
        for (int e = 0; e < 8; ++e) {
            float f = lds[pl][cl + e];
            u16 hb = f2bf(f);
            hv[e] = hb;
            lv[e] = f2bf(f - bf2f(hb));
        }
        *(u16x8*)(qhb + (size_t)pl * CC + cl) = hv;
        *(u16x8*)(qlb + (size_t)pl * CC + cl) = lv;
    }
}

// ---------------------------------------------------------------------------
// Kernel 2: V[b][o][p] = sum_c W[o][c] * X[b][c][p] + bias[o]  (bf16 out)
// A-frags from global W (fp32->bf16 on the fly, L2-resident),
// B-frags from qhi ([p][c] layout -> contiguous k). 16x16x32 MFMA.
// ---------------------------------------------------------------------------
__global__ __launch_bounds__(256, 2) void k_vgemm(const u16* __restrict__ qhi,
                                                  const float* __restrict__ w,
                                                  const float* __restrict__ bias,
                                                  u16* __restrict__ vbf) {
    int bid = blockIdx.x;
    int b = bid >> 4, pt = bid & 15;
    int t = threadIdx.x;
    int wave = t >> 6, lane = t & 63;
    int l15 = lane & 15, l4 = lane >> 4;
    int p0 = pt * 64, o0 = wave * 64;
    f32x4 acc[4][4];
#pragma unroll
    for (int m = 0; m < 4; ++m)
#pragma unroll
        for (int n = 0; n < 4; ++n) acc[m][n] = (f32x4){0.f, 0.f, 0.f, 0.f};
#pragma unroll
    for (int ks = 0; ks < 8; ++ks) {
        int kk = ks * 32 + 8 * l4;
        bf16x8 afr[4], bfr[4];
#pragma unroll
        for (int m = 0; m < 4; ++m) {
            const float* wp = w + (size_t)(o0 + m * 16 + l15) * CC + kk;
            float4 w0 = *(const float4*)wp;
            float4 w1 = *(const float4*)(wp + 4);
            u16x8 tv;
            tv[0] = f2bf(w0.x); tv[1] = f2bf(w0.y); tv[2] = f2bf(w0.z); tv[3] = f2bf(w0.w);
            tv[4] = f2bf(w1.x); tv[5] = f2bf(w1.y); tv[6] = f2bf(w1.z); tv[7] = f2bf(w1.w);
            afr[m] = __builtin_bit_cast(bf16x8, tv);
        }
#pragma unroll
        for (int n = 0; n < 4; ++n)
            bfr[n] = ld8(qhi + ((size_t)b * NN + p0 + n * 16 + l15) * CC + kk);
#pragma unroll
        for (int m = 0; m < 4; ++m)
#pragma unroll
            for (int n = 0; n < 4; ++n) acc[m][n] = mfma16(afr[m], bfr[n], acc[m][n]);
    }
#pragma unroll
    for (int m = 0; m < 4; ++m) {
#pragma unroll
        for (int r = 0; r < 4; ++r) {
            int o = o0 + m * 16 + 4 * l4 + r;
            float bv = bias[o];
            u16* vp = vbf + ((size_t)b * CC + o) * NN + p0 + l15;
#pragma unroll
            for (int n = 0; n < 4; ++n) vp[n * 16] = f2bf(acc[m][n][r] + bv);
        }
    }
}

// ---------------------------------------------------------------------------
// Kernel 3: fused flash attention + interleaved reshape + 2x2 maxpool.
// Block = (batch b, 64 query rows). 4 waves x 16 rows. BN=32 K/V tiles.
// Scores via bf16 hi/lo split (3 MFMA products) for fp32-like accuracy.
// ---------------------------------------------------------------------------
#define SMEM_BYTES 59392
__global__ __launch_bounds__(256, 2) void k_attn(const u16* __restrict__ qhi,
                                                 const u16* __restrict__ qlo,
                                                 const u16* __restrict__ vbf,
                                                 float* __restrict__ out) {
    __shared__ __align__(16) char smem[SMEM_BYTES];
    u16* Khi = (u16*)smem;            // [32][264]
    u16* Klo = (u16*)(smem + 16896);  // [32][264]
    u16* Vt  = (u16*)(smem + 33792);  // [256][40]
    u16* Pt  = (u16*)(smem + 54272);  // [4 waves][16][40]

    int bid = blockIdx.x;
    // XCD-aware swizzle: all 16 i-blocks of a batch land on one XCD's L2.
    int xcd = bid & 7, sidx0 = bid >> 3;
    int b = xcd * 4 + (sidx0 >> 4);
    int iblk = sidx0 & 15;
    int i0 = iblk * 64;
    int t = threadIdx.x;
    int wave = t >> 6, lane = t & 63;
    int l15 = lane & 15, l4 = lane >> 4;
    int iw = i0 + wave * 16;

    // Q fragments (hi/lo) in registers: lane holds row iw+l15, k = ks*32+8*l4..
    bf16x8 qh[8], ql[8];
    {
        const u16* qrh = qhi + ((size_t)b * NN + iw + l15) * CC;
        const u16* qrl = qlo + ((size_t)b * NN + iw + l15) * CC;
#pragma unroll
        for (int ks = 0; ks < 8; ++ks) {
            int kk = ks * 32 + 8 * l4;
            qh[ks] = ld8(qrh + kk);
            ql[ks] = ld8(qrl + kk);
        }
    }

    f32x4 oacc[16];
#pragma unroll
    for (int i = 0; i < 16; ++i) oacc[i] = (f32x4){0.f, 0.f, 0.f, 0.f};
    float mrow[4] = {-INFINITY, -INFINITY, -INFINITY, -INFINITY};
    float lrow[4] = {0.f, 0.f, 0.f, 0.f};

    u16* Pw = Pt + wave * 16 * PT_STRIDE;
    const u16* qhib = qhi + (size_t)b * NN * CC;
    const u16* qlob = qlo + (size_t)b * NN * CC;
    const u16* vbb  = vbf + (size_t)b * CC * NN;

    for (int jt = 0; jt < 32; ++jt) {
        int j0 = jt * BN;
        __syncthreads();
        // stage K tiles ([32 j][256 c] hi/lo)
#pragma unroll
        for (int it = 0; it < 4; ++it) {
            int sidx = t + it * 256;
            int row = sidx >> 5, ch = (sidx & 31) * 8;
            *(u16x8*)&Khi[row * KT_STRIDE + ch] =
                *(const u16x8*)(qhib + (size_t)(j0 + row) * CC + ch);
            *(u16x8*)&Klo[row * KT_STRIDE + ch] =
                *(const u16x8*)(qlob + (size_t)(j0 + row) * CC + ch);
        }
        // stage V tile ([256 o][32 j])
#pragma unroll
        for (int it = 0; it < 4; ++it) {
            int sidx = t + it * 256;
            int o = sidx >> 2, ch = (sidx & 3) * 8;
            *(u16x8*)&Vt[o * VT_STRIDE + ch] =
                *(const u16x8*)(vbb + (size_t)o * NN + j0 + ch);
        }
        __syncthreads();

        // S = Q.K^T via hi/lo split: qh*kh + qh*kl + ql*kh
        f32x4 s[2];
        s[0] = (f32x4){0.f, 0.f, 0.f, 0.f};
        s[1] = (f32x4){0.f, 0.f, 0.f, 0.f};
#pragma unroll
        for (int ks = 0; ks < 8; ++ks) {
            int kk = ks * 32 + 8 * l4;
#pragma unroll
            for (int nf = 0; nf < 2; ++nf) {
                bf16x8 bh = ld8(&Khi[(nf * 16 + l15) * KT_STRIDE + kk]);
                bf16x8 bl = ld8(&Klo[(nf * 16 + l15) * KT_STRIDE + kk]);
                s[nf] = mfma16(qh[ks], bh, s[nf]);
                s[nf] = mfma16(qh[ks], bl, s[nf]);
                s[nf] = mfma16(ql[ks], bh, s[nf]);
            }
        }

        // online softmax; C-frag row = 4*l4 + r, col = nf*16 + l15
#pragma unroll
        for (int r = 0; r < 4; ++r) {
            float mx = fmaxf(s[0][r], s[1][r]);
            mx = fmaxf(mx, __shfl_xor(mx, 1));
            mx = fmaxf(mx, __shfl_xor(mx, 2));
            mx = fmaxf(mx, __shfl_xor(mx, 4));
            mx = fmaxf(mx, __shfl_xor(mx, 8));
            float mnew = fmaxf(mrow[r], mx);
            float scale = __expf(mrow[r] - mnew);  // exp(-inf)=0 first time
            float p0 = __expf(s[0][r] - mnew);
            float p1 = __expf(s[1][r] - mnew);
            float rs = p0 + p1;
            rs += __shfl_xor(rs, 1);
            rs += __shfl_xor(rs, 2);
            rs += __shfl_xor(rs, 4);
            rs += __shfl_xor(rs, 8);
            lrow[r] = lrow[r] * scale + rs;
            mrow[r] = mnew;
#pragma unroll
            for (int onf = 0; onf < 16; ++onf) oacc[onf][r] *= scale;
            Pw[(4 * l4 + r) * PT_STRIDE + l15] = f2bf(p0);
            Pw[(4 * l4 + r) * PT_STRIDE + 16 + l15] = f2bf(p1);
        }
        // P transpose through LDS -> A-frag (same wave; no barrier needed)
        bf16x8 pa = ld8(&Pw[l15 * PT_STRIDE + 8 * l4]);
#pragma unroll
        for (int onf = 0; onf < 16; ++onf) {
            bf16x8 vb = ld8(&Vt[(onf * 16 + l15) * VT_STRIDE + 8 * l4]);
            oacc[onf] = mfma16(pa, vb, oacc[onf]);
        }
    }

    // normalize by softmax denominator
    float inv[4];
#pragma unroll
    for (int r = 0; r < 4; ++r) inv[r] = 1.0f / lrow[r];
#pragma unroll
    for (int onf = 0; onf < 16; ++onf)
#pragma unroll
        for (int r = 0; r < 4; ++r) oacc[onf][r] *= inv[r];

    // Epilogue: 2-pass through LDS (32 rows/pass), interleaved reshape + maxpool.
    // out[b][i>>2][(i&3)*4+pl][pw] = max over O[b][i][{(2pl+dy)*32 + 2pw+dx}]
    float* Old = (float*)smem;  // [32][260]
#pragma unroll
    for (int half = 0; half < 2; ++half) {
        __syncthreads();
        if ((wave >> 1) == half) {
            int wrow = (wave & 1) * 16;
#pragma unroll
            for (int onf = 0; onf < 16; ++onf)
#pragma unroll
                for (int r = 0; r < 4; ++r)
                    Old[(wrow + 4 * l4 + r) * 260 + onf * 16 + l15] = oacc[onf][r];
        }
        __syncthreads();
#pragma unroll
        for (int it = 0; it < 8; ++it) {
            int q = it * 16 + (t >> 4);
            int ill = q >> 2, pl = q & 3, pw = t & 15;
            const float* row = &Old[ill * 260];
            int ob = pl * 64 + pw * 2;
            float mx = fmaxf(fmaxf(row[ob], row[ob + 1]),
                             fmaxf(row[ob + 32], row[ob + 33]));
            int i = i0 + half * 32 + ill;
            out[(((size_t)b * CC + (i >> 2)) * 16 + (i & 3) * 4 + pl) * 16 + pw] = mx;
        }
    }
}

// ---------------------------------------------------------------------------
extern "C" void kernel_launch(void* const* d_in, const int* in_sizes, int n_in,
                              void* d_out, int out_size, void* d_ws, size_t ws_size,
                              hipStream_t stream) {
    const float* x = (const float*)d_in[0];
    const float* w = (const float*)d_in[1];
    const float* bias = (const float*)d_in[2];
    float* out = (float*)d_out;
    u16* qhi = (u16*)d_ws;                     // [32][1024][256] bf16
    u16* qlo = qhi + (size_t)BB * NN * CC;     // [32][1024][256] bf16
    u16* vbf = qlo + (size_t)BB * NN * CC;     // [32][256][1024] bf16
    k_split<<<2048, 256, 0, stream>>>(x, qhi, qlo);
    k_vgemm<<<512, 256, 0, stream>>>(qhi, w, bias, vbf);
    k_attn<<<512, 256, 0, stream>>>(qhi, qlo, vbf, out);
}